// Round 9
// baseline (216.672 us; speedup 1.0000x reference)
//
#include <hip/hip_runtime.h>
#include <hip/hip_bf16.h>
#include <stdint.h>

// BertSelfAttention: B=4, S=2048, D=1024, H=16, HD=64
// Pipeline: [cvt: X,W -> bf16 once] ->
//   per head-chunk: [qkv_gemm: bf16 MFMA, global_load_lds staging, fused RoPE,
//                    Q/K -> [bh,s,hd], V -> V^T [bh,hd,s] directly]
//                   [attn: flash attention, fixed-max softmax, async-staged K/V]
// NOTE: no s_setprio — measured regression on this barrier-lockstep structure
// (attn ~100 -> 144.5 us when added in R7; matches learn_hip m190).

typedef __attribute__((ext_vector_type(4))) float    f32x4;
typedef __attribute__((ext_vector_type(8))) __bf16   bf16x8;
typedef __attribute__((ext_vector_type(8))) unsigned short ushort8;
typedef __attribute__((ext_vector_type(4))) unsigned short ushort4v;

// 0.125 (1/sqrt(64)) * log2(e): scores come out in exp2-domain
#define QSCALE 0.18033688011112042f
#define SMAX   16.0f   // fixed softmax "max": exact (power-of-2 scale), scores |s|<~9

#define GLOAD_LDS16(g, l)                                                     \
  __builtin_amdgcn_global_load_lds(                                           \
      (const __attribute__((address_space(1))) void*)(g),                     \
      (__attribute__((address_space(3))) void*)(l), 16, 0, 0)

__device__ inline unsigned short bf(float f) {
  return __builtin_bit_cast(unsigned short, (__bf16)f);
}

// ---------------- f32 -> bf16 convert pre-pass ----------------
__global__ __launch_bounds__(256) void cvt_bf16(
    const float* __restrict__ X,
    const float* __restrict__ Wq, const float* __restrict__ Wk,
    const float* __restrict__ Wv,
    unsigned short* __restrict__ Xb, unsigned short* __restrict__ Wb)
{
  const int seg = blockIdx.y;
  const float* __restrict__ src = (seg == 0) ? X : (seg == 1) ? Wq : (seg == 2) ? Wk : Wv;
  unsigned short* __restrict__ dst = (seg == 0) ? Xb : Wb + (size_t)(seg - 1) * 1048576;
  const size_t n8 = (seg == 0) ? (size_t)1048576 : (size_t)131072;  // chunks of 8
  const size_t stride = (size_t)gridDim.x * 256;
  for (size_t i = blockIdx.x * 256 + threadIdx.x; i < n8; i += stride) {
    const float4 a = *reinterpret_cast<const float4*>(src + i * 8);
    const float4 b = *reinterpret_cast<const float4*>(src + i * 8 + 4);
    ushort8 o = { bf(a.x), bf(a.y), bf(a.z), bf(a.w), bf(b.x), bf(b.y), bf(b.z), bf(b.w) };
    *reinterpret_cast<ushort8*>(dst + i * 8) = o;
  }
}

// ---------------- QKV GEMM (bf16, global_load_lds) + fused RoPE ----------------
__global__ __launch_bounds__(256) void qkv_gemm(
    const unsigned short* __restrict__ Xb, const unsigned short* __restrict__ Wb,
    const float* __restrict__ rc, const float* __restrict__ rs,
    unsigned short* __restrict__ Qb, unsigned short* __restrict__ Kb,
    unsigned short* __restrict__ VbT, int col0, int nheads_c, int gx)
{
  const int nwg = gridDim.x;
  const int q8 = nwg >> 3;
  int w = (blockIdx.x % 8) * q8 + blockIdx.x / 8;
  const int z = w / (gx * 64);
  const int r = w - z * gx * 64;
  const int brow = (r / gx) * 128;
  const int bcol = (r % gx) * 128;

  const unsigned short* __restrict__ Wz = Wb + (size_t)z * 1048576;

  const int tid  = threadIdx.x;
  const int lane = tid & 63;
  const int wid  = tid >> 6;
  const int wm = wid >> 1, wn = wid & 1;     // 2x2 waves, each 64x64
  const int col16 = lane & 15, rowg = lane >> 4;

  __shared__ unsigned short As[128 * 32];    // linear (global_load_lds dest)
  __shared__ unsigned short Bs[128 * 32];

  f32x4 acc[4][4];
  #pragma unroll
  for (int m = 0; m < 4; ++m)
    #pragma unroll
    for (int n = 0; n < 4; ++n) acc[m][n] = (f32x4)0.f;

  const int srow = wid * 16 + (lane >> 2);
  const int scol = (lane & 3) * 8;
  const unsigned short* gA0 = Xb + (size_t)(brow + srow) * 1024 + scol;
  const unsigned short* gA1 = gA0 + (size_t)64 * 1024;
  const unsigned short* gB0 = Wz + (size_t)(col0 + bcol + srow) * 1024 + scol;
  const unsigned short* gB1 = gB0 + (size_t)64 * 1024;
  unsigned short* lA0 = &As[wid * 16 * 32];
  unsigned short* lA1 = &As[(64 + wid * 16) * 32];
  unsigned short* lB0 = &Bs[wid * 16 * 32];
  unsigned short* lB1 = &Bs[(64 + wid * 16) * 32];

  for (int k0 = 0; k0 < 1024; k0 += 32) {
    GLOAD_LDS16(gA0 + k0, lA0);
    GLOAD_LDS16(gA1 + k0, lA1);
    GLOAD_LDS16(gB0 + k0, lB0);
    GLOAD_LDS16(gB1 + k0, lB1);
    __syncthreads();

    bf16x8 af[4], bfv[4];
    #pragma unroll
    for (int m = 0; m < 4; ++m)
      af[m] = __builtin_bit_cast(bf16x8, *reinterpret_cast<const ushort8*>(
                &As[(wm * 64 + m * 16 + col16) * 32 + rowg * 8]));
    #pragma unroll
    for (int n = 0; n < 4; ++n)
      bfv[n] = __builtin_bit_cast(bf16x8, *reinterpret_cast<const ushort8*>(
                &Bs[(wn * 64 + n * 16 + col16) * 32 + rowg * 8]));
    #pragma unroll
    for (int m = 0; m < 4; ++m)
      #pragma unroll
      for (int n = 0; n < 4; ++n)
        acc[m][n] = __builtin_amdgcn_mfma_f32_16x16x32_bf16(af[m], bfv[n], acc[m][n], 0, 0, 0);
    __syncthreads();
  }

  #pragma unroll
  for (int m = 0; m < 4; ++m) {
    #pragma unroll
    for (int n = 0; n < 4; ++n) {
      const int e  = bcol + wn * 64 + n * 16 + col16;   // chunk-local feature
      const int hl = e >> 6, hd = e & 63;               // chunk-local head
      if (z == 2) {
        const int row0 = brow + wm * 64 + m * 16 + rowg * 4;
        const int b = row0 >> 11, s0 = row0 & 2047;
        ushort4v o = { bf(acc[m][n][0]), bf(acc[m][n][1]), bf(acc[m][n][2]), bf(acc[m][n][3]) };
        *reinterpret_cast<ushort4v*>(
            VbT + ((size_t)(b * nheads_c + hl) * 64 + hd) * 2048 + s0) = o;
      } else {
        unsigned short* __restrict__ outp = (z == 0) ? Qb : Kb;
        #pragma unroll
        for (int j = 0; j < 4; ++j) {
          const int row = brow + wm * 64 + m * 16 + rowg * 4 + j;
          const int b = row >> 11, s = row & 2047;
          const float rot = (n < 2) ? -acc[m][n + 2][j] : acc[m][n - 2][j];
          float v = acc[m][n][j] * rc[s * 64 + hd] + rot * rs[s * 64 + hd];
          if (z == 0) v *= QSCALE;
          outp[((size_t)(b * nheads_c + hl) * 2048 + s) * 64 + hd] = bf(v);
        }
      }
    }
  }
}

// ---------------- Flash attention (fixed-max softmax, async-staged K/V) ----------------
// Per tile: [QKT reads Ks -> softmax -> P write -> sync -> PV reads Vt,Ps -> sync
//            -> write prefetched K/V(t+1) -> sync].  Loads for t+1 issue before
//  QKT so HBM/L2 latency hides under compute (T14).
__global__ __launch_bounds__(256) void attn(
    const unsigned short* __restrict__ Qb, const unsigned short* __restrict__ Kb,
    const unsigned short* __restrict__ VbT, float* __restrict__ out,
    int col0, int nheads_c)
{
  const int tid = threadIdx.x, lane = tid & 63, wq = tid >> 6;
  const int col16 = lane & 15, rowg = lane >> 4;

  // XCD-aware bijective swizzle (nwg is a multiple of 128)
  int wg = blockIdx.x;
  const int qx = (int)gridDim.x >> 3;
  wg = (wg & 7) * qx + (wg >> 3);
  const int bh = wg >> 4;
  const int q0 = (wg & 15) * 128;
  const int b = bh / nheads_c, hl = bh - b * nheads_c;
  const int hg = (col0 >> 6) + hl;
  const size_t base = (size_t)bh * 2048 * 64;

  __shared__ unsigned short Ks[64 * 72];   // [key][hd], +8 pad
  __shared__ unsigned short Vt[64 * 72];   // [hd][key], +8 pad
  __shared__ unsigned short Ps[128 * 76];  // [q][key]; +12 pad; doubles as Q staging

  const int r  = tid >> 3, c  = (tid & 7) * 8;
  const int vr = tid >> 2, vc = (tid & 3) * 16;

  // stage Q tile -> Ps and K/V tile 0
  #pragma unroll
  for (int p = 0; p < 4; ++p) {
    const int row = p * 32 + r;
    ushort8 v = *reinterpret_cast<const ushort8*>(Qb + base + (size_t)(q0 + row) * 64 + c);
    *reinterpret_cast<ushort8*>(&Ps[row * 76 + c]) = v;
  }
  {
    ushort8 k0 = *reinterpret_cast<const ushort8*>(Kb + base + (size_t)r * 64 + c);
    ushort8 k1 = *reinterpret_cast<const ushort8*>(Kb + base + (size_t)(32 + r) * 64 + c);
    ushort8 v0 = *reinterpret_cast<const ushort8*>(VbT + base + (size_t)vr * 2048 + vc);
    ushort8 v1 = *reinterpret_cast<const ushort8*>(VbT + base + (size_t)vr * 2048 + vc + 8);
    *reinterpret_cast<ushort8*>(&Ks[r * 72 + c]) = k0;
    *reinterpret_cast<ushort8*>(&Ks[(32 + r) * 72 + c]) = k1;
    *reinterpret_cast<ushort8*>(&Vt[vr * 72 + vc]) = v0;
    *reinterpret_cast<ushort8*>(&Vt[vr * 72 + vc + 8]) = v1;
  }
  __syncthreads();

  bf16x8 qf[2][2];
  #pragma unroll
  for (int m = 0; m < 2; ++m)
    #pragma unroll
    for (int ks = 0; ks < 2; ++ks)
      qf[m][ks] = __builtin_bit_cast(bf16x8, *reinterpret_cast<const ushort8*>(
          &Ps[(wq * 32 + m * 16 + col16) * 76 + ks * 32 + rowg * 8]));

  float lsum[2][4];
  f32x4 acc[2][4];
  #pragma unroll
  for (int m = 0; m < 2; ++m)
    #pragma unroll
    for (int j = 0; j < 4; ++j) lsum[m][j] = 0.f;
  #pragma unroll
  for (int m = 0; m < 2; ++m)
    #pragma unroll
    for (int hf = 0; hf < 4; ++hf) acc[m][hf] = (f32x4)0.f;

  for (int kt = 0; kt < 32; ++kt) {
    // T14: issue next tile's loads early; latency hides under QKT+SM+PV
    ushort8 nk0, nk1, nv0, nv1;
    if (kt < 31) {
      const int kn = (kt + 1) * 64;
      nk0 = *reinterpret_cast<const ushort8*>(Kb + base + (size_t)(kn + r) * 64 + c);
      nk1 = *reinterpret_cast<const ushort8*>(Kb + base + (size_t)(kn + 32 + r) * 64 + c);
      nv0 = *reinterpret_cast<const ushort8*>(VbT + base + (size_t)vr * 2048 + kn + vc);
      nv1 = *reinterpret_cast<const ushort8*>(VbT + base + (size_t)vr * 2048 + kn + vc + 8);
    }

    // S*log2e = Q @ K^T (Q pre-scaled) -> col=key(lane&15), row=q
    f32x4 sc[2][4];
    #pragma unroll
    for (int m = 0; m < 2; ++m)
      #pragma unroll
      for (int kf = 0; kf < 4; ++kf) sc[m][kf] = (f32x4)0.f;
    #pragma unroll
    for (int kf = 0; kf < 4; ++kf) {
      #pragma unroll
      for (int ks = 0; ks < 2; ++ks) {
        bf16x8 kfrag = __builtin_bit_cast(bf16x8, *reinterpret_cast<const ushort8*>(
            &Ks[(kf * 16 + col16) * 72 + ks * 32 + rowg * 8]));
        sc[0][kf] = __builtin_amdgcn_mfma_f32_16x16x32_bf16(qf[0][ks], kfrag, sc[0][kf], 0, 0, 0);
        sc[1][kf] = __builtin_amdgcn_mfma_f32_16x16x32_bf16(qf[1][ks], kfrag, sc[1][kf], 0, 0, 0);
      }
    }

    // fixed-max softmax: p = exp2(s - 16) (power-of-2 scale of true numerator)
    #pragma unroll
    for (int m = 0; m < 2; ++m)
      #pragma unroll
      for (int j = 0; j < 4; ++j) {
        float ps = 0.f;
        #pragma unroll
        for (int kf = 0; kf < 4; ++kf) {
          const float p = __builtin_exp2f(sc[m][kf][j] - SMAX);
          sc[m][kf][j] = p;
          ps += p;
        }
        lsum[m][j] += ps;
      }

    // P -> LDS (bf16), 76-pad: 2-way write aliasing only (free)
    #pragma unroll
    for (int m = 0; m < 2; ++m)
      #pragma unroll
      for (int kf = 0; kf < 4; ++kf)
        #pragma unroll
        for (int j = 0; j < 4; ++j)
          Ps[(wq * 32 + m * 16 + rowg * 4 + j) * 76 + kf * 16 + col16] = bf(sc[m][kf][j]);
    __syncthreads();

    // O += P @ V
    #pragma unroll
    for (int ks = 0; ks < 2; ++ks) {
      bf16x8 pf[2];
      #pragma unroll
      for (int m = 0; m < 2; ++m)
        pf[m] = __builtin_bit_cast(bf16x8, *reinterpret_cast<const ushort8*>(
            &Ps[(wq * 32 + m * 16 + col16) * 76 + ks * 32 + rowg * 8]));
      #pragma unroll
      for (int hf = 0; hf < 4; ++hf) {
        bf16x8 vf = __builtin_bit_cast(bf16x8, *reinterpret_cast<const ushort8*>(
            &Vt[(hf * 16 + col16) * 72 + ks * 32 + rowg * 8]));
        acc[0][hf] = __builtin_amdgcn_mfma_f32_16x16x32_bf16(pf[0], vf, acc[0][hf], 0, 0, 0);
        acc[1][hf] = __builtin_amdgcn_mfma_f32_16x16x32_bf16(pf[1], vf, acc[1][hf], 0, 0, 0);
      }
    }
    __syncthreads();                       // all waves done reading Ks/Vt

    if (kt < 31) {
      *reinterpret_cast<ushort8*>(&Ks[r * 72 + c]) = nk0;
      *reinterpret_cast<ushort8*>(&Ks[(32 + r) * 72 + c]) = nk1;
      *reinterpret_cast<ushort8*>(&Vt[vr * 72 + vc]) = nv0;
      *reinterpret_cast<ushort8*>(&Vt[vr * 72 + vc + 8]) = nv1;
      __syncthreads();                     // next tile staged
    }
  }

  // final lsum reduce across the 16-lane group, normalize + write [B,S,D] f32
  #pragma unroll
  for (int m = 0; m < 2; ++m)
    #pragma unroll
    for (int j = 0; j < 4; ++j) {
      float l = lsum[m][j];
      l += __shfl_xor(l, 1);
      l += __shfl_xor(l, 2);
      l += __shfl_xor(l, 4);
      l += __shfl_xor(l, 8);
      const float inv = 1.0f / l;
      const int s = q0 + wq * 32 + m * 16 + rowg * 4 + j;
      #pragma unroll
      for (int hf = 0; hf < 4; ++hf) {
        const int hd = hf * 16 + col16;
        out[((size_t)(b * 2048 + s)) * 1024 + hg * 64 + hd] = acc[m][hf][j] * inv;
      }
    }
}

extern "C" void kernel_launch(void* const* d_in, const int* in_sizes, int n_in,
                              void* d_out, int out_size, void* d_ws, size_t ws_size,
                              hipStream_t stream) {
  (void)in_sizes; (void)n_in; (void)out_size;
  const float* X  = (const float*)d_in[0];
  const float* rc = (const float*)d_in[2];
  const float* rs = (const float*)d_in[3];
  const float* Wq = (const float*)d_in[4];
  const float* Wk = (const float*)d_in[5];
  const float* Wv = (const float*)d_in[6];
  float* out = (float*)d_out;

  // ws: [Qb|Kb|VbT] (48MB/NC) + Xb (16MB) + Wb (6MB). NC = pure fn of ws_size.
  const size_t fixed = (size_t)2 * 8192 * 1024 + (size_t)3 * 2 * 1024 * 1024;
  int NC = 8;
  for (int nc = 1; nc <= 8; nc <<= 1) {
    size_t need = (size_t)3 * 2 * 8192 * (1024 / nc) + fixed;
    if (need <= ws_size) { NC = nc; break; }
  }
  const int CW = 1024 / NC;
  const int nheads_c = CW >> 6;
  const int nBH = 4 * nheads_c;
  const int gx = CW / 128;
  const size_t pc = (size_t)8192 * CW;

  unsigned short* Qb  = (unsigned short*)d_ws;
  unsigned short* Kb  = Qb + pc;
  unsigned short* VbT = Kb + pc;
  unsigned short* Xb  = VbT + pc;
  unsigned short* Wb  = Xb + (size_t)8192 * 1024;

  cvt_bf16<<<dim3(512, 4), 256, 0, stream>>>(X, Wq, Wk, Wv, Xb, Wb);

  for (int c = 0; c < NC; ++c) {
    const int col0 = c * CW;
    qkv_gemm<<<dim3(gx * 64 * 3), 256, 0, stream>>>(
        Xb, Wb, rc, rs, Qb, Kb, VbT, col0, nheads_c, gx);
    attn<<<dim3(16 * nBH), 256, 0, stream>>>(
        Qb, Kb, VbT, out, col0, nheads_c);
  }
}

// Round 10
// 206.153 us; speedup vs baseline: 1.0510x; 1.0510x over previous
//
#include <hip/hip_runtime.h>
#include <hip/hip_bf16.h>
#include <stdint.h>

// BertSelfAttention: B=4, S=2048, D=1024, H=16, HD=64
// Pipeline: [cvt: X,W -> bf16 once] ->
//   per head-chunk: [qkv_gemm: bf16 MFMA, global_load_lds staging, fused RoPE,
//                    Q/K -> [bh,s,hd], V -> V^T [bh,hd,s] directly]
//                   [attn: flash attention, fixed-max softmax, serial staging]
// MEASURED (this session): s_setprio on this lockstep structure: attn 95->144us
// (R6 A/B). Reg-held K/V prefetch: also regresses (R8, 157us) because the
// mid-tile P-barrier's vmcnt(0) drains the loads anyway while VGPR 60->76
// cuts occupancy 35->26%. Both are reverted; do not re-add.

typedef __attribute__((ext_vector_type(4))) float    f32x4;
typedef __attribute__((ext_vector_type(8))) __bf16   bf16x8;
typedef __attribute__((ext_vector_type(8))) unsigned short ushort8;
typedef __attribute__((ext_vector_type(4))) unsigned short ushort4v;

// 0.125 (1/sqrt(64)) * log2(e): scores come out in exp2-domain
#define QSCALE 0.18033688011112042f
#define SMAX   16.0f   // fixed softmax "max": exact (power-of-2 scale), scores |s|<~9

#define GLOAD_LDS16(g, l)                                                     \
  __builtin_amdgcn_global_load_lds(                                           \
      (const __attribute__((address_space(1))) void*)(g),                     \
      (__attribute__((address_space(3))) void*)(l), 16, 0, 0)

__device__ inline unsigned short bf(float f) {
  return __builtin_bit_cast(unsigned short, (__bf16)f);
}

// ---------------- f32 -> bf16 convert pre-pass ----------------
__global__ __launch_bounds__(256) void cvt_bf16(
    const float* __restrict__ X,
    const float* __restrict__ Wq, const float* __restrict__ Wk,
    const float* __restrict__ Wv,
    unsigned short* __restrict__ Xb, unsigned short* __restrict__ Wb)
{
  const int seg = blockIdx.y;
  const float* __restrict__ src = (seg == 0) ? X : (seg == 1) ? Wq : (seg == 2) ? Wk : Wv;
  unsigned short* __restrict__ dst = (seg == 0) ? Xb : Wb + (size_t)(seg - 1) * 1048576;
  const size_t n8 = (seg == 0) ? (size_t)1048576 : (size_t)131072;  // chunks of 8
  const size_t stride = (size_t)gridDim.x * 256;
  for (size_t i = blockIdx.x * 256 + threadIdx.x; i < n8; i += stride) {
    const float4 a = *reinterpret_cast<const float4*>(src + i * 8);
    const float4 b = *reinterpret_cast<const float4*>(src + i * 8 + 4);
    ushort8 o = { bf(a.x), bf(a.y), bf(a.z), bf(a.w), bf(b.x), bf(b.y), bf(b.z), bf(b.w) };
    *reinterpret_cast<ushort8*>(dst + i * 8) = o;
  }
}

// ---------------- QKV GEMM (bf16, global_load_lds) + fused RoPE ----------------
__global__ __launch_bounds__(256) void qkv_gemm(
    const unsigned short* __restrict__ Xb, const unsigned short* __restrict__ Wb,
    const float* __restrict__ rc, const float* __restrict__ rs,
    unsigned short* __restrict__ Qb, unsigned short* __restrict__ Kb,
    unsigned short* __restrict__ VbT, int col0, int nheads_c, int gx)
{
  const int nwg = gridDim.x;
  const int q8 = nwg >> 3;
  int w = (blockIdx.x % 8) * q8 + blockIdx.x / 8;
  const int z = w / (gx * 64);
  const int r = w - z * gx * 64;
  const int brow = (r / gx) * 128;
  const int bcol = (r % gx) * 128;

  const unsigned short* __restrict__ Wz = Wb + (size_t)z * 1048576;

  const int tid  = threadIdx.x;
  const int lane = tid & 63;
  const int wid  = tid >> 6;
  const int wm = wid >> 1, wn = wid & 1;     // 2x2 waves, each 64x64
  const int col16 = lane & 15, rowg = lane >> 4;

  __shared__ unsigned short As[128 * 32];    // linear (global_load_lds dest)
  __shared__ unsigned short Bs[128 * 32];

  f32x4 acc[4][4];
  #pragma unroll
  for (int m = 0; m < 4; ++m)
    #pragma unroll
    for (int n = 0; n < 4; ++n) acc[m][n] = (f32x4)0.f;

  const int srow = wid * 16 + (lane >> 2);
  const int scol = (lane & 3) * 8;
  const unsigned short* gA0 = Xb + (size_t)(brow + srow) * 1024 + scol;
  const unsigned short* gA1 = gA0 + (size_t)64 * 1024;
  const unsigned short* gB0 = Wz + (size_t)(col0 + bcol + srow) * 1024 + scol;
  const unsigned short* gB1 = gB0 + (size_t)64 * 1024;
  unsigned short* lA0 = &As[wid * 16 * 32];
  unsigned short* lA1 = &As[(64 + wid * 16) * 32];
  unsigned short* lB0 = &Bs[wid * 16 * 32];
  unsigned short* lB1 = &Bs[(64 + wid * 16) * 32];

  for (int k0 = 0; k0 < 1024; k0 += 32) {
    GLOAD_LDS16(gA0 + k0, lA0);
    GLOAD_LDS16(gA1 + k0, lA1);
    GLOAD_LDS16(gB0 + k0, lB0);
    GLOAD_LDS16(gB1 + k0, lB1);
    __syncthreads();

    bf16x8 af[4], bfv[4];
    #pragma unroll
    for (int m = 0; m < 4; ++m)
      af[m] = __builtin_bit_cast(bf16x8, *reinterpret_cast<const ushort8*>(
                &As[(wm * 64 + m * 16 + col16) * 32 + rowg * 8]));
    #pragma unroll
    for (int n = 0; n < 4; ++n)
      bfv[n] = __builtin_bit_cast(bf16x8, *reinterpret_cast<const ushort8*>(
                &Bs[(wn * 64 + n * 16 + col16) * 32 + rowg * 8]));
    #pragma unroll
    for (int m = 0; m < 4; ++m)
      #pragma unroll
      for (int n = 0; n < 4; ++n)
        acc[m][n] = __builtin_amdgcn_mfma_f32_16x16x32_bf16(af[m], bfv[n], acc[m][n], 0, 0, 0);
    __syncthreads();
  }

  #pragma unroll
  for (int m = 0; m < 4; ++m) {
    #pragma unroll
    for (int n = 0; n < 4; ++n) {
      const int e  = bcol + wn * 64 + n * 16 + col16;   // chunk-local feature
      const int hl = e >> 6, hd = e & 63;               // chunk-local head
      if (z == 2) {
        const int row0 = brow + wm * 64 + m * 16 + rowg * 4;
        const int b = row0 >> 11, s0 = row0 & 2047;
        ushort4v o = { bf(acc[m][n][0]), bf(acc[m][n][1]), bf(acc[m][n][2]), bf(acc[m][n][3]) };
        *reinterpret_cast<ushort4v*>(
            VbT + ((size_t)(b * nheads_c + hl) * 64 + hd) * 2048 + s0) = o;
      } else {
        unsigned short* __restrict__ outp = (z == 0) ? Qb : Kb;
        #pragma unroll
        for (int j = 0; j < 4; ++j) {
          const int row = brow + wm * 64 + m * 16 + rowg * 4 + j;
          const int b = row >> 11, s = row & 2047;
          const float rot = (n < 2) ? -acc[m][n + 2][j] : acc[m][n - 2][j];
          float v = acc[m][n][j] * rc[s * 64 + hd] + rot * rs[s * 64 + hd];
          if (z == 0) v *= QSCALE;
          outp[((size_t)(b * nheads_c + hl) * 2048 + s) * 64 + hd] = bf(v);
        }
      }
    }
  }
}

// ---------------- Flash attention (fixed-max softmax, serial staging) ----------------
// Per tile: [stage K/V -> sync -> QKT -> softmax -> P write -> sync -> PV -> sync]
__global__ __launch_bounds__(256) void attn(
    const unsigned short* __restrict__ Qb, const unsigned short* __restrict__ Kb,
    const unsigned short* __restrict__ VbT, float* __restrict__ out,
    int col0, int nheads_c)
{
  const int tid = threadIdx.x, lane = tid & 63, wq = tid >> 6;
  const int col16 = lane & 15, rowg = lane >> 4;

  // XCD-aware bijective swizzle (nwg is a multiple of 128)
  int wg = blockIdx.x;
  const int qx = (int)gridDim.x >> 3;
  wg = (wg & 7) * qx + (wg >> 3);
  const int bh = wg >> 4;
  const int q0 = (wg & 15) * 128;
  const int b = bh / nheads_c, hl = bh - b * nheads_c;
  const int hg = (col0 >> 6) + hl;
  const size_t base = (size_t)bh * 2048 * 64;

  __shared__ unsigned short Ks[64 * 72];   // [key][hd], +8 pad
  __shared__ unsigned short Vt[64 * 72];   // [hd][key], +8 pad
  __shared__ unsigned short Ps[128 * 76];  // [q][key]; +12 pad; doubles as Q staging

  const int r  = tid >> 3, c  = (tid & 7) * 8;
  const int vr = tid >> 2, vc = (tid & 3) * 16;

  // stage Q tile -> Ps
  #pragma unroll
  for (int p = 0; p < 4; ++p) {
    const int row = p * 32 + r;
    ushort8 v = *reinterpret_cast<const ushort8*>(Qb + base + (size_t)(q0 + row) * 64 + c);
    *reinterpret_cast<ushort8*>(&Ps[row * 76 + c]) = v;
  }
  __syncthreads();
  bf16x8 qf[2][2];
  #pragma unroll
  for (int m = 0; m < 2; ++m)
    #pragma unroll
    for (int ks = 0; ks < 2; ++ks)
      qf[m][ks] = __builtin_bit_cast(bf16x8, *reinterpret_cast<const ushort8*>(
          &Ps[(wq * 32 + m * 16 + col16) * 76 + ks * 32 + rowg * 8]));

  float lsum[2][4];
  f32x4 acc[2][4];
  #pragma unroll
  for (int m = 0; m < 2; ++m)
    #pragma unroll
    for (int j = 0; j < 4; ++j) lsum[m][j] = 0.f;
  #pragma unroll
  for (int m = 0; m < 2; ++m)
    #pragma unroll
    for (int hf = 0; hf < 4; ++hf) acc[m][hf] = (f32x4)0.f;

  for (int kt = 0; kt < 32; ++kt) {
    const int key0 = kt * 64;
    // stage K (row-major) and V^T (transposed in global already)
    {
      ushort8 k0 = *reinterpret_cast<const ushort8*>(Kb + base + (size_t)(key0 + r) * 64 + c);
      ushort8 k1 = *reinterpret_cast<const ushort8*>(Kb + base + (size_t)(key0 + 32 + r) * 64 + c);
      ushort8 v0 = *reinterpret_cast<const ushort8*>(VbT + base + (size_t)vr * 2048 + key0 + vc);
      ushort8 v1 = *reinterpret_cast<const ushort8*>(VbT + base + (size_t)vr * 2048 + key0 + vc + 8);
      *reinterpret_cast<ushort8*>(&Ks[r * 72 + c]) = k0;
      *reinterpret_cast<ushort8*>(&Ks[(32 + r) * 72 + c]) = k1;
      *reinterpret_cast<ushort8*>(&Vt[vr * 72 + vc]) = v0;
      *reinterpret_cast<ushort8*>(&Vt[vr * 72 + vc + 8]) = v1;
    }
    __syncthreads();

    // S*log2e = Q @ K^T (Q pre-scaled) -> col=key(lane&15), row=q
    f32x4 sc[2][4];
    #pragma unroll
    for (int m = 0; m < 2; ++m)
      #pragma unroll
      for (int kf = 0; kf < 4; ++kf) sc[m][kf] = (f32x4)0.f;
    #pragma unroll
    for (int kf = 0; kf < 4; ++kf) {
      #pragma unroll
      for (int ks = 0; ks < 2; ++ks) {
        bf16x8 kfrag = __builtin_bit_cast(bf16x8, *reinterpret_cast<const ushort8*>(
            &Ks[(kf * 16 + col16) * 72 + ks * 32 + rowg * 8]));
        sc[0][kf] = __builtin_amdgcn_mfma_f32_16x16x32_bf16(qf[0][ks], kfrag, sc[0][kf], 0, 0, 0);
        sc[1][kf] = __builtin_amdgcn_mfma_f32_16x16x32_bf16(qf[1][ks], kfrag, sc[1][kf], 0, 0, 0);
      }
    }

    // fixed-max softmax: p = exp2(s - 16) (power-of-2 scale of true numerator)
    #pragma unroll
    for (int m = 0; m < 2; ++m)
      #pragma unroll
      for (int j = 0; j < 4; ++j) {
        float ps = 0.f;
        #pragma unroll
        for (int kf = 0; kf < 4; ++kf) {
          const float p = __builtin_exp2f(sc[m][kf][j] - SMAX);
          sc[m][kf][j] = p;
          ps += p;
        }
        lsum[m][j] += ps;
      }

    // P -> LDS (bf16), 76-pad: write aliasing 2-way only (free)
    #pragma unroll
    for (int m = 0; m < 2; ++m)
      #pragma unroll
      for (int kf = 0; kf < 4; ++kf)
        #pragma unroll
        for (int j = 0; j < 4; ++j)
          Ps[(wq * 32 + m * 16 + rowg * 4 + j) * 76 + kf * 16 + col16] = bf(sc[m][kf][j]);
    __syncthreads();

    // O += P @ V
    #pragma unroll
    for (int ks = 0; ks < 2; ++ks) {
      bf16x8 pf[2];
      #pragma unroll
      for (int m = 0; m < 2; ++m)
        pf[m] = __builtin_bit_cast(bf16x8, *reinterpret_cast<const ushort8*>(
            &Ps[(wq * 32 + m * 16 + col16) * 76 + ks * 32 + rowg * 8]));
      #pragma unroll
      for (int hf = 0; hf < 4; ++hf) {
        bf16x8 vf = __builtin_bit_cast(bf16x8, *reinterpret_cast<const ushort8*>(
            &Vt[(hf * 16 + col16) * 72 + ks * 32 + rowg * 8]));
        acc[0][hf] = __builtin_amdgcn_mfma_f32_16x16x32_bf16(pf[0], vf, acc[0][hf], 0, 0, 0);
        acc[1][hf] = __builtin_amdgcn_mfma_f32_16x16x32_bf16(pf[1], vf, acc[1][hf], 0, 0, 0);
      }
    }
    __syncthreads();
  }

  // final lsum reduce across the 16-lane group, normalize + write [B,S,D] f32
  #pragma unroll
  for (int m = 0; m < 2; ++m)
    #pragma unroll
    for (int j = 0; j < 4; ++j) {
      float l = lsum[m][j];
      l += __shfl_xor(l, 1);
      l += __shfl_xor(l, 2);
      l += __shfl_xor(l, 4);
      l += __shfl_xor(l, 8);
      const float inv = 1.0f / l;
      const int s = q0 + wq * 32 + m * 16 + rowg * 4 + j;
      #pragma unroll
      for (int hf = 0; hf < 4; ++hf) {
        const int hd = hf * 16 + col16;
        out[((size_t)(b * 2048 + s)) * 1024 + hg * 64 + hd] = acc[m][hf][j] * inv;
      }
    }
}

extern "C" void kernel_launch(void* const* d_in, const int* in_sizes, int n_in,
                              void* d_out, int out_size, void* d_ws, size_t ws_size,
                              hipStream_t stream) {
  (void)in_sizes; (void)n_in; (void)out_size;
  const float* X  = (const float*)d_in[0];
  const float* rc = (const float*)d_in[2];
  const float* rs = (const float*)d_in[3];
  const float* Wq = (const float*)d_in[4];
  const float* Wk = (const float*)d_in[5];
  const float* Wv = (const float*)d_in[6];
  float* out = (float*)d_out;

  // ws: [Qb|Kb|VbT] (48MB/NC) + Xb (16MB) + Wb (6MB). NC = pure fn of ws_size.
  const size_t fixed = (size_t)2 * 8192 * 1024 + (size_t)3 * 2 * 1024 * 1024;
  int NC = 8;
  for (int nc = 1; nc <= 8; nc <<= 1) {
    size_t need = (size_t)3 * 2 * 8192 * (1024 / nc) + fixed;
    if (need <= ws_size) { NC = nc; break; }
  }
  const int CW = 1024 / NC;
  const int nheads_c = CW >> 6;
  const int nBH = 4 * nheads_c;
  const int gx = CW / 128;
  const size_t pc = (size_t)8192 * CW;

  unsigned short* Qb  = (unsigned short*)d_ws;
  unsigned short* Kb  = Qb + pc;
  unsigned short* VbT = Kb + pc;
  unsigned short* Xb  = VbT + pc;
  unsigned short* Wb  = Xb + (size_t)8192 * 1024;

  cvt_bf16<<<dim3(512, 4), 256, 0, stream>>>(X, Wq, Wk, Wv, Xb, Wb);

  for (int c = 0; c < NC; ++c) {
    const int col0 = c * CW;
    qkv_gemm<<<dim3(gx * 64 * 3), 256, 0, stream>>>(
        Xb, Wb, rc, rs, Qb, Kb, VbT, col0, nheads_c, gx);
    attn<<<dim3(16 * nBH), 256, 0, stream>>>(
        Qb, Kb, VbT, out, col0, nheads_c);
  }
}